// Round 4
// baseline (135.794 us; speedup 1.0000x reference)
//
#include <hip/hip_runtime.h>

#define NB 2048
#define NJ 22
#define ND 128
#define ROW4 (NJ * ND / 4)   // 704 float4 per i-row
#define YB4  (NJ * ND / 4)   // 704 float4 per batch of Y

typedef float f32x4 __attribute__((ext_vector_type(4)));

// ---------------- Kernel A: Y[b][j][e] = sum_d src[b][j][d] * W[e][d] ----------------
__global__ __launch_bounds__(256, 4) void gemm_y(
    const float* __restrict__ src, const float* __restrict__ W,
    float* __restrict__ Y) {
  __shared__ float srcS[NJ * ND];  // [j][d]
  __shared__ float YS[NJ * ND];    // [j][e]

  const int b = blockIdx.x;
  const int t = threadIdx.x;
  const float* srcB = src + (size_t)b * NJ * ND;

  for (int idx = t; idx < NJ * ND / 4; idx += 256) {
    reinterpret_cast<f32x4*>(srcS)[idx] =
        reinterpret_cast<const f32x4*>(srcB)[idx];
  }

  const int e  = t & 127;  // output feature this thread owns
  const int dh = t >> 7;   // d-half (0/1)

  float w[64];
  {
    const f32x4* Wrow = reinterpret_cast<const f32x4*>(W + e * ND + dh * 64);
#pragma unroll
    for (int k = 0; k < 16; ++k) {
      f32x4 v = Wrow[k];
      w[4 * k + 0] = v.x;
      w[4 * k + 1] = v.y;
      w[4 * k + 2] = v.z;
      w[4 * k + 3] = v.w;
    }
  }
  __syncthreads();  // srcS ready

  for (int c = 0; c < 2; ++c) {  // two chunks of 11 rows: VGPR < 128
    float acc[11];
#pragma unroll
    for (int jj = 0; jj < 11; ++jj) {
      const int j = c * 11 + jj;
      const f32x4* s4 = reinterpret_cast<const f32x4*>(srcS + j * ND + dh * 64);
      float a = 0.f;
#pragma unroll
      for (int k = 0; k < 16; ++k) {
        f32x4 s = s4[k];  // wave-uniform address -> LDS broadcast
        a += s.x * w[4 * k + 0];
        a += s.y * w[4 * k + 1];
        a += s.z * w[4 * k + 2];
        a += s.w * w[4 * k + 3];
      }
      acc[jj] = a;
    }
    if (dh == 0) {
#pragma unroll
      for (int jj = 0; jj < 11; ++jj) YS[(c * 11 + jj) * ND + e] = acc[jj];
    }
    __syncthreads();
    if (dh == 1) {
#pragma unroll
      for (int jj = 0; jj < 11; ++jj) YS[(c * 11 + jj) * ND + e] += acc[jj];
    }
  }
  __syncthreads();  // YS complete

  // write Y[b] coalesced
  f32x4* Yb4 = reinterpret_cast<f32x4*>(Y + (size_t)b * NJ * ND);
  const f32x4* YS4 = reinterpret_cast<const f32x4*>(YS);
  Yb4[t] = YS4[t];
  Yb4[t + 256] = YS4[t + 256];
  if (t < 192) Yb4[t + 512] = YS4[t + 512];
}

// ---------------- Kernel B: pure streaming expansion ----------------
// out[b][i][j][e] = Y[b][j][e] - Y[b][i][e] + bias[e]
__global__ __launch_bounds__(256, 8) void expand(
    const float* __restrict__ Y, const float* __restrict__ bias,
    float* __restrict__ out) {
  __shared__ float YS[NJ * ND];  // 11 KB -> 8 blocks/CU fits LDS

  const int b = blockIdx.x;
  const int t = threadIdx.x;

  // stage Y[b] -> LDS (L2-hot: Y is 23 MB, just written)
  const f32x4* Yb4 = reinterpret_cast<const f32x4*>(Y + (size_t)b * NJ * ND);
  f32x4* YS4w = reinterpret_cast<f32x4*>(YS);
  YS4w[t] = Yb4[t];
  YS4w[t + 256] = Yb4[t + 256];
  if (t < 192) YS4w[t + 512] = Yb4[t + 512];
  __syncthreads();

  // Flat float4 index within an i-row: q = jx*32 + e4,  q = t + 256*k.
  // This thread always writes rows {j0, j0+8, j0+16} at column e4.
  const int e4 = t & 31;
  const int j0 = t >> 5;  // 0..7
  const f32x4* YS4 = reinterpret_cast<const f32x4*>(YS);
  const f32x4 bb4 = reinterpret_cast<const f32x4*>(bias)[e4];

  f32x4 yj0 = YS4[j0 * 32 + e4] + bb4;
  f32x4 yj1 = YS4[(j0 + 8) * 32 + e4] + bb4;
  f32x4 yj2 = {0.f, 0.f, 0.f, 0.f};
  if (j0 < 6) yj2 = YS4[(j0 + 16) * 32 + e4] + bb4;

  f32x4* outB4 = reinterpret_cast<f32x4*>(out + (size_t)b * NJ * NJ * ND);

  for (int ii = 0; ii < NJ; ++ii) {
    f32x4 yi = YS4[ii * 32 + e4];
    f32x4* outRow4 = outB4 + (size_t)ii * ROW4;
    outRow4[t] = yj0 - yi;
    outRow4[t + 256] = yj1 - yi;
    if (j0 < 6) outRow4[t + 512] = yj2 - yi;
  }
}

extern "C" void kernel_launch(void* const* d_in, const int* in_sizes, int n_in,
                              void* d_out, int out_size, void* d_ws, size_t ws_size,
                              hipStream_t stream) {
  const float* src  = (const float*)d_in[0];  // [2048, 22, 128] f32
  const float* W    = (const float*)d_in[1];  // [128, 128] f32, W[e][d]
  const float* bias = (const float*)d_in[2];  // [128] f32
  float* out = (float*)d_out;                 // [2048, 22, 22, 128] f32
  float* Yw  = (float*)d_ws;                  // [2048, 22, 128] f32 = 23.1 MB

  gemm_y<<<NB, 256, 0, stream>>>(src, W, Yw);
  expand<<<NB, 256, 0, stream>>>(Yw, bias, out);
}